// Round 15
// baseline (247.993 us; speedup 1.0000x reference)
//
#include <hip/hip_runtime.h>

#define B_ 8
#define C_ 256
#define N_ 4096
#define NSPLIT 16

typedef float f32x4 __attribute__((ext_vector_type(4)));
typedef __bf16 bf16x8 __attribute__((ext_vector_type(8)));
typedef __bf16 bf16x4 __attribute__((ext_vector_type(4)));
typedef unsigned short u16x8 __attribute__((ext_vector_type(8)));
typedef unsigned short u16x4 __attribute__((ext_vector_type(4)));

// Native cast: compiler emits v_cvt_pk_bf16_f32 for adjacent pairs (RNE).
__device__ __forceinline__ unsigned short f2bf(float f) {
  return __builtin_bit_cast(unsigned short, (__bf16)f);
}
__device__ __forceinline__ float bf2f(unsigned short u) {
  return __uint_as_float((unsigned)u << 16);
}

__device__ __forceinline__ f32x4 mfma16(bf16x8 a, bf16x8 b, f32x4 c) {
  return __builtin_amdgcn_mfma_f32_16x16x32_bf16(a, b, c, 0, 0, 0);
}

typedef __attribute__((address_space(1))) const void* gvp;
typedef __attribute__((address_space(3))) void* lvp;
__device__ __forceinline__ void gld16(const void* g, void* l) {
  __builtin_amdgcn_global_load_lds((gvp)g, (lvp)l, 16, 0, 0);
}

// Counted waits + raw barrier (T4 pattern; neutral but harmless per R13).
#define VMWAIT(N) do { asm volatile("s_waitcnt vmcnt(" #N ")" ::: "memory"); \
                       __builtin_amdgcn_sched_barrier(0); } while (0)
#define BAR() __builtin_amdgcn_s_barrier()

// Swizzled LDS tile (bf16 sources): ROWS x 64 bf16, pitch 64 u16; chunk c of
// row r at slot c^(r&7). Staged with global_load_lds (16 B/lane, async).
// Per-wave vmem count: ROWS/32 instructions.
template <int ROWS>
__device__ __forceinline__ void stage(unsigned short* lds, const unsigned short* g,
                                      int ld, int w, int lane) {
  const int r8 = lane >> 3;
  const int ce = ((lane & 7) ^ r8) << 3;
  const unsigned short* gp = g + (size_t)(w * (ROWS / 4) + r8) * ld + ce;
  unsigned short* lp = lds + w * (ROWS / 4) * 64;
#pragma unroll
  for (int i = 0; i < ROWS / 32; i++)
    gld16(gp + (size_t)(i * 8) * ld, lp + i * 512);
}

__device__ __forceinline__ bf16x8 frag(const unsigned short* lds, int row, int kc) {
  return *(const bf16x8*)(lds + row * 64 + ((kc ^ (row & 7)) << 3));
}

// Fused-transpose B tile (fp32 [k][n] source -> bf16 [n][k] LDS).
// Pitch 70 u16 (35 dwords, odd stride): writeB 2-way (free, m136), fragB
// reads spread over all 32 banks. PMC-validated in R14: bank conflicts
// 2.36M -> 262K (9x) vs the old pitch-68 layout.
#define BPITCH 70
__device__ __forceinline__ void loadB(float4* pbv, const float* src, int ld,
                                      int n0, int kt, int w, int lane) {
  const int nf = lane & 15, kg = lane >> 4;
  const float* sp = src + (size_t)(kt * 64 + w * 16 + kg * 4) * ld + n0 + 4 * nf;
#pragma unroll
  for (int h = 0; h < 2; h++)
#pragma unroll
    for (int i = 0; i < 4; i++)
      pbv[h * 4 + i] = *(const float4*)(sp + h * 64 + (size_t)i * ld);
}
__device__ __forceinline__ void writeB(unsigned short* Bs, const float4* pbv,
                                       int w, int lane) {
  const int nf = lane & 15, kg = lane >> 4;
  const int k0 = w * 16 + kg * 4;
#pragma unroll
  for (int h = 0; h < 2; h++)
#pragma unroll
    for (int j = 0; j < 4; j++) {
      bf16x4 o = (bf16x4){(__bf16)((const float*)&pbv[h * 4 + 0])[j],
                          (__bf16)((const float*)&pbv[h * 4 + 1])[j],
                          (__bf16)((const float*)&pbv[h * 4 + 2])[j],
                          (__bf16)((const float*)&pbv[h * 4 + 3])[j]};
      *(bf16x4*)&Bs[(h * 64 + 4 * nf + j) * BPITCH + k0] = o;
    }
}
__device__ __forceinline__ bf16x8 fragB(const unsigned short* Bs, int n, int k8) {
  union { u16x4 q[2]; bf16x8 b; } u;
  const unsigned short* p = Bs + n * BPITCH + k8 * 8;
  u.q[0] = *(const u16x4*)p;
  u.q[1] = *(const u16x4*)(p + 4);
  return u.b;
}

// ctx^T tile in LDS, pitch 268 u16 (row stride 6 banks mod 32 -> conflict-free).
__device__ __forceinline__ bf16x8 fragC(const unsigned short* Ct, int n, int k8) {
  union { u16x4 q[2]; bf16x8 b; } u;
  const unsigned short* p = Ct + n * 268 + k8 * 8;
  u.q[0] = *(const u16x4*)p;
  u.q[1] = *(const u16x4*)(p + 4);
  return u.b;
}

// ---------------------------------------------------------------------------
// P1: cast weights fp32 -> bf16; zero the K-softmax denominator accumulator.
__global__ __launch_bounds__(256) void castw(
    const float* __restrict__ wq, const float* __restrict__ wkv,
    const float* __restrict__ wo, unsigned short* __restrict__ wqb,
    unsigned short* __restrict__ wkvb, unsigned short* __restrict__ wob,
    float* __restrict__ Z) {
  int t = blockIdx.x * 256 + threadIdx.x;
  if (t < B_ * C_) Z[t] = 0.f;
  int i = t * 4;
  const float* src;
  unsigned short* dst;
  int off;
  if (i < 65536) { src = wq; dst = wqb; off = i; }
  else if (i < 196608) { src = wkv; dst = wkvb; off = i - 65536; }
  else { src = wo; dst = wob; off = i - 196608; }
  float4 v = *(const float4*)(src + off);
  *(u16x4*)(dst + off) = (u16x4){f2bf(v.x), f2bf(v.y), f2bf(v.z), f2bf(v.w)};
}

// ---------------------------------------------------------------------------
// qproj path: qT[b][n][m] = softmax_d((wq @ x + bq) * 0.25). M-tile 128
// (2 heads) x N-tile 128, BK=64. Wave (w>>1) owns one head; (w&1) a 64-col
// half. acc[4][4].
__device__ __forceinline__ void qproj_body(
    unsigned short* As, unsigned short* Bs, const unsigned short* __restrict__ wqb,
    const float* __restrict__ x, const float* __restrict__ bq,
    unsigned short* __restrict__ qT, int b, int n0, int m0b) {
  const int tid = threadIdx.x, lane = tid & 63, w = tid >> 6;
  const int m0w = (w >> 1) * 64;
  const int n0w = (w & 1) * 64;
  const int colL = lane & 15, kq = lane >> 4, quad = lane >> 4;
  const float* xb = x + (size_t)b * C_ * N_;

  f32x4 acc[4][4];
#pragma unroll
  for (int i = 0; i < 4; i++)
#pragma unroll
    for (int j = 0; j < 4; j++) acc[i][j] = (f32x4){0.f, 0.f, 0.f, 0.f};

  float4 pbv[8];
  loadB(pbv, xb, N_, n0, 0, w, lane);

  for (int kt = 0; kt < 4; kt++) {
    writeB(Bs, pbv, w, lane);
    stage<128>(As, wqb + (size_t)m0b * C_ + kt * 64, C_, w, lane);
    __syncthreads();
    if (kt < 3) loadB(pbv, xb, N_, n0, kt + 1, w, lane);
#pragma unroll
    for (int ks = 0; ks < 2; ks++) {
      bf16x8 af[4], bf[4];
#pragma unroll
      for (int mt = 0; mt < 4; mt++) af[mt] = frag(As, m0w + mt * 16 + colL, ks * 4 + kq);
#pragma unroll
      for (int nt = 0; nt < 4; nt++) bf[nt] = fragB(Bs, n0w + nt * 16 + colL, ks * 4 + kq);
#pragma unroll
      for (int mt = 0; mt < 4; mt++)
#pragma unroll
        for (int nt = 0; nt < 4; nt++) acc[mt][nt] = mfma16(af[mt], bf[nt], acc[mt][nt]);
    }
    __syncthreads();
  }

  // per-column softmax over this wave's head (64 channels)
#pragma unroll
  for (int nt = 0; nt < 4; nt++) {
    float v[16];
    float mx = -1e30f;
#pragma unroll
    for (int mt = 0; mt < 4; mt++)
#pragma unroll
      for (int r = 0; r < 4; r++) {
        int m = m0b + m0w + mt * 16 + quad * 4 + r;
        float val = (acc[mt][nt][r] + bq[m]) * 0.25f;
        v[mt * 4 + r] = val;
        mx = fmaxf(mx, val);
      }
    mx = fmaxf(mx, __shfl_xor(mx, 16));
    mx = fmaxf(mx, __shfl_xor(mx, 32));
    float s = 0.f;
#pragma unroll
    for (int j = 0; j < 16; j++) { v[j] = __expf(v[j] - mx); s += v[j]; }
    s += __shfl_xor(s, 16);
    s += __shfl_xor(s, 32);
    float inv = 1.0f / s;
    const int n = n0 + n0w + nt * 16 + colL;
    unsigned short* qb = qT + ((size_t)b * N_ + n) * C_ + m0b + m0w;
#pragma unroll
    for (int mt = 0; mt < 4; mt++) {
      u16x4 o = (u16x4){f2bf(v[mt * 4 + 0] * inv), f2bf(v[mt * 4 + 1] * inv),
                        f2bf(v[mt * 4 + 2] * inv), f2bf(v[mt * 4 + 3] * inv)};
      *(u16x4*)(qb + mt * 16 + quad * 4) = o;
    }
  }
}

// kvproj path: KV = wkv @ cproj + bkv. M-tile 128 x N-tile 128. acc[2][8].
// Epilogue: K rows -> Eb = bf16(exp(K+b)) + rowsum Z atomics; V rows -> bf16.
__device__ __forceinline__ void kvproj_body(
    unsigned short* As, unsigned short* Bs, const unsigned short* __restrict__ wkvb,
    const float* __restrict__ cp, const float* __restrict__ bkv,
    unsigned short* __restrict__ Eb, unsigned short* __restrict__ Vb,
    float* __restrict__ Z, int b, int n0, int m0b) {
  const int tid = threadIdx.x, lane = tid & 63, w = tid >> 6;
  const int m0w = w * 32;
  const int colL = lane & 15, kq = lane >> 4, quad = lane >> 4;
  const float* cpb = cp + (size_t)b * C_ * N_;

  f32x4 acc[2][8];
#pragma unroll
  for (int i = 0; i < 2; i++)
#pragma unroll
    for (int j = 0; j < 8; j++) acc[i][j] = (f32x4){0.f, 0.f, 0.f, 0.f};

  float4 pbv[8];
  loadB(pbv, cpb, N_, n0, 0, w, lane);

  for (int kt = 0; kt < 4; kt++) {
    writeB(Bs, pbv, w, lane);
    stage<128>(As, wkvb + (size_t)m0b * C_ + kt * 64, C_, w, lane);
    __syncthreads();
    if (kt < 3) loadB(pbv, cpb, N_, n0, kt + 1, w, lane);
#pragma unroll
    for (int ks = 0; ks < 2; ks++) {
      bf16x8 bf[8];
#pragma unroll
      for (int nt = 0; nt < 8; nt++) bf[nt] = fragB(Bs, nt * 16 + colL, ks * 4 + kq);
#pragma unroll
      for (int mt = 0; mt < 2; mt++) {
        bf16x8 af = frag(As, m0w + mt * 16 + colL, ks * 4 + kq);
#pragma unroll
        for (int nt = 0; nt < 8; nt++) acc[mt][nt] = mfma16(af, bf[nt], acc[mt][nt]);
      }
    }
    __syncthreads();
  }

#pragma unroll
  for (int mt = 0; mt < 2; mt++)
#pragma unroll
    for (int r = 0; r < 4; r++) {
      int m = m0b + m0w + mt * 16 + quad * 4 + r;
      float bias = bkv[m];
      if (m < C_) {
        unsigned short* er = Eb + ((size_t)b * C_ + m) * N_ + n0;
        float es = 0.f;
#pragma unroll
        for (int nt = 0; nt < 8; nt++) {
          float e = __expf(acc[mt][nt][r] + bias);
          er[nt * 16 + colL] = f2bf(e);
          es += e;
        }
        // reduce over the 16 colL lanes of this quad (same m)
        es += __shfl_xor(es, 1);
        es += __shfl_xor(es, 2);
        es += __shfl_xor(es, 4);
        es += __shfl_xor(es, 8);
        if ((lane & 15) == 0) atomicAdd(&Z[b * C_ + m], es);
      } else {
        unsigned short* vr = Vb + ((size_t)b * C_ + m - C_) * N_ + n0;
#pragma unroll
        for (int nt = 0; nt < 8; nt++) vr[nt * 16 + colL] = f2bf(acc[mt][nt][r] + bias);
      }
    }
}

// G1+G2 fused: qproj (y=0..1) and kvproj (y=2..5), dispatch (32,6,8).
// Keep this 2D grid — panel-siblings are 32 apart in linear id, 32%8==0,
// so HW round-robin co-locates them per XCD; the mixed q/kv per-block phase
// timing also desynchronizes the drain bursts (R14's split regressed 4x on
// kvproj by making the whole grid co-resident and lockstep).
__global__ __launch_bounds__(256) void qkvproj(
    const unsigned short* __restrict__ wqb, const unsigned short* __restrict__ wkvb,
    const float* __restrict__ x, const float* __restrict__ cp,
    const float* __restrict__ bq, const float* __restrict__ bkv,
    unsigned short* __restrict__ qT, unsigned short* __restrict__ Eb,
    unsigned short* __restrict__ Vb, float* __restrict__ Z) {
  __shared__ __align__(16) unsigned short As[128 * 64];
  __shared__ __align__(16) unsigned short Bs[128 * BPITCH];
  const int b = blockIdx.z, n0 = blockIdx.x * 128;
  if (blockIdx.y < 2)
    qproj_body(As, Bs, wqb, x, bq, qT, b, n0, blockIdx.y * 128);
  else
    kvproj_body(As, Bs, wkvb, cp, bkv, Eb, Vb, Z, b, n0, (blockIdx.y - 2) * 128);
}

// ---------------------------------------------------------------------------
// G4: ctxp[s][b][c][d] = bf16( invz[c] * sum_{n in split s} Eb[c,n]*Vb[d,n] ).
// NT GEMM 128x128, BK=64, NSPLIT=16, XCD-chunked. T4 counted-vmcnt pipeline
// (R13 form — measured neutral, kept).
__global__ __launch_bounds__(256) void ctx_part(
    const unsigned short* __restrict__ Eb, const float* __restrict__ Z,
    const unsigned short* __restrict__ Vb, unsigned short* __restrict__ ctxp) {
  __shared__ __align__(16) unsigned short As[2][128 * 64];
  __shared__ __align__(16) unsigned short Bs[2][128 * 64];
  const int bid = blockIdx.x;
  const int swz = (bid & 7) * 64 + (bid >> 3);
  const int b = swz >> 6, r = swz & 63;
  const int s = r >> 2;
  const int m0 = ((r >> 1) & 1) * 128, n0 = (r & 1) * 128;
  const int tid = threadIdx.x, lane = tid & 63, w = tid >> 6;
  const int m0w = (w & 1) * 64, n0w = (w >> 1) * 64;
  const int colL = lane & 15, kq = lane >> 4, quad = lane >> 4;
  const unsigned short* Ag = Eb + ((size_t)b * C_ + m0) * N_ + s * (N_ / NSPLIT);
  const unsigned short* Bg = Vb + ((size_t)b * C_ + n0) * N_ + s * (N_ / NSPLIT);

  f32x4 acc[4][4];
#pragma unroll
  for (int i = 0; i < 4; i++)
#pragma unroll
    for (int j = 0; j < 4; j++) acc[i][j] = (f32x4){0.f, 0.f, 0.f, 0.f};

  stage<128>(As[0], Ag + 0 * 64, N_, w, lane);
  stage<128>(Bs[0], Bg + 0 * 64, N_, w, lane);
  stage<128>(As[1], Ag + 1 * 64, N_, w, lane);
  stage<128>(Bs[1], Bg + 1 * 64, N_, w, lane);
  VMWAIT(8);   // tile 0 landed (tile 1's 8 still in flight)
  BAR();

  for (int kt = 0; kt < 4; kt++) {
    const unsigned short* Asc = As[kt & 1];
    const unsigned short* Bsc = Bs[kt & 1];
#pragma unroll
    for (int ks = 0; ks < 2; ks++) {
      bf16x8 af[4], bf[4];
#pragma unroll
      for (int mt = 0; mt < 4; mt++) af[mt] = frag(Asc, m0w + mt * 16 + colL, ks * 4 + kq);
#pragma unroll
      for (int nt = 0; nt < 4; nt++) bf[nt] = frag(Bsc, n0w + nt * 16 + colL, ks * 4 + kq);
#pragma unroll
      for (int mt = 0; mt < 4; mt++)
#pragma unroll
        for (int nt = 0; nt < 4; nt++) acc[mt][nt] = mfma16(af[mt], bf[nt], acc[mt][nt]);
    }
    if (kt == 3) break;
    BAR();                                  // all waves done reading buf[kt&1]
    if (kt + 2 < 4) {
      stage<128>(As[kt & 1], Ag + (kt + 2) * 64, N_, w, lane);
      stage<128>(Bs[kt & 1], Bg + (kt + 2) * 64, N_, w, lane);
      VMWAIT(8);                            // tile kt+1 landed; kt+2 in flight
    } else {
      VMWAIT(0);                            // final tile (issued one iter ago)
    }
    BAR();
  }

  unsigned short* outp = ctxp + ((size_t)s * B_ + b) * C_ * C_;
  const float* Zb = Z + b * C_;
#pragma unroll
  for (int mt = 0; mt < 4; mt++)
#pragma unroll
    for (int r2 = 0; r2 < 4; r2++) {
      int m = m0 + m0w + mt * 16 + quad * 4 + r2;
      float iz = 1.0f / Zb[m];
#pragma unroll
      for (int nt = 0; nt < 4; nt++) {
        int n = n0 + n0w + nt * 16 + colL;
        outp[(size_t)m * C_ + n] = f2bf(acc[mt][nt][r2] * iz);
      }
    }
}

// ---------------------------------------------------------------------------
// R+G5 fused: ctx2[b][o][d] = wo @ (sum_s ctxp[s]). XCD-chunked: 256 blocks
// 1D, chunk 32 = one b -> ctxp[.][b] (2 MB) + wob (0.5 MB) in one L2.
__global__ __launch_bounds__(256) void ctxoproj(
    const unsigned short* __restrict__ ctxp, const unsigned short* __restrict__ wob,
    unsigned short* __restrict__ ctx2) {
  __shared__ __align__(16) unsigned short AsW[4 * 64 * 64];
  __shared__ __align__(16) unsigned short Ct[32 * 268];
  const int bid = blockIdx.x;
  const int swz = (bid & 7) * 32 + (bid >> 3);
  const int b = swz >> 5, r = swz & 31;
  const int o0 = (r >> 3) * 64, d0 = (r & 7) * 32;
  const int tid = threadIdx.x, lane = tid & 63, w = tid >> 6;
  const int colL = lane & 15, kq = lane >> 4, quad = lane >> 4;

  // wo tile 64 x 256 bf16, all 4 k-chunks async up front (hidden under phase 1)
#pragma unroll
  for (int ck = 0; ck < 4; ck++)
    stage<64>(AsW + ck * 4096, wob + (size_t)o0 * C_ + ck * 64, C_, w, lane);

  // phase 1: Ct[d][c] = sum_s ctxp[s][b][c][d0+d] (bf16 in, fp32 accumulate)
  const int q = tid & 7, cl = tid >> 3;   // q: d-quad (4 d), cl: c within pass
  const unsigned short* pb = ctxp + ((size_t)b * C_ + cl) * C_ + d0 + q * 4;
#pragma unroll 2
  for (int p = 0; p < 8; p++) {
    f32x4 s4 = (f32x4){0.f, 0.f, 0.f, 0.f};
    const unsigned short* pp = pb + (size_t)p * 32 * C_;
#pragma unroll
    for (int s = 0; s < NSPLIT; s++) {
      u16x4 v = *(const u16x4*)(pp + (size_t)s * B_ * C_ * C_);
      s4[0] += bf2f(v[0]); s4[1] += bf2f(v[1]);
      s4[2] += bf2f(v[2]); s4[3] += bf2f(v[3]);
    }
    const int c = p * 32 + cl;
#pragma unroll
    for (int j = 0; j < 4; j++) Ct[(q * 4 + j) * 268 + c] = f2bf(s4[j]);
  }
  __syncthreads();

  // phase 2: per wave 16 o-rows x 32 d-cols, K = 256
  f32x4 acc2[2];
  acc2[0] = (f32x4){0.f, 0.f, 0.f, 0.f};
  acc2[1] = (f32x4){0.f, 0.f, 0.f, 0.f};
#pragma unroll
  for (int kt = 0; kt < 4; kt++)
#pragma unroll
    for (int ks = 0; ks < 2; ks++) {
      bf16x8 af = frag(AsW + kt * 4096, w * 16 + colL, ks * 4 + kq);
#pragma unroll
      for (int nt = 0; nt < 2; nt++) {
        bf16x8 bf = fragC(Ct, nt * 16 + colL, kt * 8 + ks * 4 + kq);
        acc2[nt] = mfma16(af, bf, acc2[nt]);
      }
    }
  unsigned short* ob = ctx2 + (size_t)b * C_ * C_;
#pragma unroll
  for (int nt = 0; nt < 2; nt++)
#pragma unroll
    for (int r2 = 0; r2 < 4; r2++)
      ob[(size_t)(o0 + w * 16 + quad * 4 + r2) * C_ + d0 + nt * 16 + colL] =
          f2bf(acc2[nt][r2]);
}

// ---------------------------------------------------------------------------
// G6: out[b][m][n] = sum_d ctx2[b][m][d] * qT[b][n][d] + bo[m]. NT GEMM,
// M-tile 128 x N-tile 64, BK=64, XCD-chunked, T4 counted-vmcnt pipeline
// (6 gld_lds/wave/tile -> vmcnt(6)). R13 form.
__global__ __launch_bounds__(256) void outgemm(
    const unsigned short* __restrict__ ctx2, const unsigned short* __restrict__ qT,
    const float* __restrict__ bo, float* __restrict__ out) {
  __shared__ __align__(16) unsigned short As[2][128 * 64];
  __shared__ __align__(16) unsigned short Bs[2][64 * 64];
  const int bid = blockIdx.x;
  const int swz = (bid & 7) * 128 + (bid >> 3);
  const int b = swz >> 7, r = swz & 127;
  const int m0b = (r >> 6) * 128, n0 = (r & 63) * 64;
  const int tid = threadIdx.x, lane = tid & 63, w = tid >> 6;
  const int m0w = w * 32;
  const int colL = lane & 15, kq = lane >> 4, quad = lane >> 4;
  const unsigned short* Ag = ctx2 + (size_t)b * C_ * C_ + (size_t)m0b * C_;
  const unsigned short* Bg = qT + ((size_t)b * N_ + n0) * C_;

  f32x4 acc[2][4];
#pragma unroll
  for (int i = 0; i < 2; i++)
#pragma unroll
    for (int j = 0; j < 4; j++) acc[i][j] = (f32x4){0.f, 0.f, 0.f, 0.f};

  stage<128>(As[0], Ag + 0 * 64, C_, w, lane);
  stage<64>(Bs[0], Bg + 0 * 64, C_, w, lane);
  stage<128>(As[1], Ag + 1 * 64, C_, w, lane);
  stage<64>(Bs[1], Bg + 1 * 64, C_, w, lane);
  VMWAIT(6);   // tile 0 landed (tile 1's 6 in flight)
  BAR();

  for (int kt = 0; kt < 4; kt++) {
    const unsigned short* Asc = As[kt & 1];
    const unsigned short* Bsc = Bs[kt & 1];
#pragma unroll
    for (int ks = 0; ks < 2; ks++) {
      bf16x8 af[2], bf[4];
#pragma unroll
      for (int mt = 0; mt < 2; mt++) af[mt] = frag(Asc, m0w + mt * 16 + colL, ks * 4 + kq);
#pragma unroll
      for (int nt = 0; nt < 4; nt++) bf[nt] = frag(Bsc, nt * 16 + colL, ks * 4 + kq);
#pragma unroll
      for (int mt = 0; mt < 2; mt++)
#pragma unroll
        for (int nt = 0; nt < 4; nt++) acc[mt][nt] = mfma16(af[mt], bf[nt], acc[mt][nt]);
    }
    if (kt == 3) break;
    BAR();
    if (kt + 2 < 4) {
      stage<128>(As[kt & 1], Ag + (kt + 2) * 64, C_, w, lane);
      stage<64>(Bs[kt & 1], Bg + (kt + 2) * 64, C_, w, lane);
      VMWAIT(6);
    } else {
      VMWAIT(0);
    }
    BAR();
  }

  float* ob = out + (size_t)b * C_ * N_;
#pragma unroll
  for (int mt = 0; mt < 2; mt++)
#pragma unroll
    for (int r2 = 0; r2 < 4; r2++) {
      int m = m0b + m0w + mt * 16 + quad * 4 + r2;
      float bias = bo[m];
#pragma unroll
      for (int nt = 0; nt < 4; nt++) {
        int n = n0 + nt * 16 + colL;
        ob[(size_t)m * N_ + n] = acc[mt][nt][r2] + bias;
      }
    }
}

// ---------------------------------------------------------------------------
extern "C" void kernel_launch(void* const* d_in, const int* in_sizes, int n_in,
                              void* d_out, int out_size, void* d_ws, size_t ws_size,
                              hipStream_t stream) {
  const float* x     = (const float*)d_in[0];
  const float* cproj = (const float*)d_in[1];
  const float* wq    = (const float*)d_in[2];
  const float* bq    = (const float*)d_in[3];
  const float* wkv   = (const float*)d_in[4];
  const float* bkv   = (const float*)d_in[5];
  const float* wo    = (const float*)d_in[6];
  const float* bo    = (const float*)d_in[7];
  float* out = (float*)d_out;

  // workspace (~70 MB)
  unsigned short* qT    = (unsigned short*)d_ws;            // 8.39M u16
  unsigned short* Eb    = qT + 8388608;                     // 8.39M u16
  unsigned short* Vb    = Eb + 8388608;                     // 8.39M u16
  unsigned short* ctxp  = Vb + 8388608;                     // 8.39M u16 (16 splits, bf16)
  unsigned short* wqb   = ctxp + 8388608;
  unsigned short* wkvb  = wqb + 65536;
  unsigned short* wob   = wkvb + 131072;
  unsigned short* ctx2  = wob + 65536;                      // 524288 u16
  float*          Zbuf  = (float*)(ctx2 + 524288);          // 2048 f32

  castw<<<256, 256, 0, stream>>>(wq, wkv, wo, wqb, wkvb, wob, Zbuf);
  qkvproj<<<dim3(32, 6, 8), 256, 0, stream>>>(wqb, wkvb, x, cproj, bq, bkv,
                                              qT, Eb, Vb, Zbuf);
  ctx_part<<<512, 256, 0, stream>>>(Eb, Zbuf, Vb, ctxp);
  ctxoproj<<<256, 256, 0, stream>>>(ctxp, wob, ctx2);
  outgemm<<<1024, 256, 0, stream>>>(ctx2, qT, bo, out);
}

// Round 16
// 182.707 us; speedup vs baseline: 1.3573x; 1.3573x over previous
//
#include <hip/hip_runtime.h>

#define B_ 8
#define C_ 256
#define N_ 4096
#define NSPLIT 16

typedef float f32x4 __attribute__((ext_vector_type(4)));
typedef __bf16 bf16x8 __attribute__((ext_vector_type(8)));
typedef __bf16 bf16x4 __attribute__((ext_vector_type(4)));
typedef unsigned short u16x8 __attribute__((ext_vector_type(8)));
typedef unsigned short u16x4 __attribute__((ext_vector_type(4)));

// Native cast: compiler emits v_cvt_pk_bf16_f32 for adjacent pairs (RNE).
__device__ __forceinline__ unsigned short f2bf(float f) {
  return __builtin_bit_cast(unsigned short, (__bf16)f);
}
__device__ __forceinline__ float bf2f(unsigned short u) {
  return __uint_as_float((unsigned)u << 16);
}

__device__ __forceinline__ f32x4 mfma16(bf16x8 a, bf16x8 b, f32x4 c) {
  return __builtin_amdgcn_mfma_f32_16x16x32_bf16(a, b, c, 0, 0, 0);
}

typedef __attribute__((address_space(1))) const void* gvp;
typedef __attribute__((address_space(3))) void* lvp;
__device__ __forceinline__ void gld16(const void* g, void* l) {
  __builtin_amdgcn_global_load_lds((gvp)g, (lvp)l, 16, 0, 0);
}

// Counted waits + raw barrier (T4 pattern; neutral but harmless per R13).
#define VMWAIT(N) do { asm volatile("s_waitcnt vmcnt(" #N ")" ::: "memory"); \
                       __builtin_amdgcn_sched_barrier(0); } while (0)
#define BAR() __builtin_amdgcn_s_barrier()

// Swizzled LDS tile (bf16 sources): ROWS x 64 bf16, pitch 64 u16; chunk c of
// row r at slot c^(r&7). Staged with global_load_lds (16 B/lane, async).
// Per-wave vmem count: ROWS/32 instructions.
template <int ROWS>
__device__ __forceinline__ void stage(unsigned short* lds, const unsigned short* g,
                                      int ld, int w, int lane) {
  const int r8 = lane >> 3;
  const int ce = ((lane & 7) ^ r8) << 3;
  const unsigned short* gp = g + (size_t)(w * (ROWS / 4) + r8) * ld + ce;
  unsigned short* lp = lds + w * (ROWS / 4) * 64;
#pragma unroll
  for (int i = 0; i < ROWS / 32; i++)
    gld16(gp + (size_t)(i * 8) * ld, lp + i * 512);
}

__device__ __forceinline__ bf16x8 frag(const unsigned short* lds, int row, int kc) {
  return *(const bf16x8*)(lds + row * 64 + ((kc ^ (row & 7)) << 3));
}

// Fused-transpose B tile (fp32 [k][n] source -> bf16 [n][k] LDS, pitch 68).
// PITCH MUST BE == 0 mod 4 u16: bf16x4/u16x4 accesses need 8 B alignment.
// R15's pitch-70 "bank fix" broke alignment -> every ds op split to b32 ->
// qkvproj 53 -> 124 us. Pitch 68 (even dword stride, mild 4-way conflicts)
// is the measured-best form.
__device__ __forceinline__ void loadB(float4* pbv, const float* src, int ld,
                                      int n0, int kt, int w, int lane) {
  const int nf = lane & 15, kg = lane >> 4;
  const float* sp = src + (size_t)(kt * 64 + w * 16 + kg * 4) * ld + n0 + 4 * nf;
#pragma unroll
  for (int h = 0; h < 2; h++)
#pragma unroll
    for (int i = 0; i < 4; i++)
      pbv[h * 4 + i] = *(const float4*)(sp + h * 64 + (size_t)i * ld);
}
__device__ __forceinline__ void writeB(unsigned short* Bs, const float4* pbv,
                                       int w, int lane) {
  const int nf = lane & 15, kg = lane >> 4;
  const int k0 = w * 16 + kg * 4;
#pragma unroll
  for (int h = 0; h < 2; h++)
#pragma unroll
    for (int j = 0; j < 4; j++) {
      bf16x4 o = (bf16x4){(__bf16)((const float*)&pbv[h * 4 + 0])[j],
                          (__bf16)((const float*)&pbv[h * 4 + 1])[j],
                          (__bf16)((const float*)&pbv[h * 4 + 2])[j],
                          (__bf16)((const float*)&pbv[h * 4 + 3])[j]};
      *(bf16x4*)&Bs[(h * 64 + 4 * nf + j) * 68 + k0] = o;
    }
}
__device__ __forceinline__ bf16x8 fragB(const unsigned short* Bs, int n, int k8) {
  union { u16x4 q[2]; bf16x8 b; } u;
  const unsigned short* p = Bs + n * 68 + k8 * 8;
  u.q[0] = *(const u16x4*)p;
  u.q[1] = *(const u16x4*)(p + 4);
  return u.b;
}

// ctx^T tile in LDS, pitch 268 u16 (0 mod 4; row stride 6 banks mod 32 ->
// conflict-free).
__device__ __forceinline__ bf16x8 fragC(const unsigned short* Ct, int n, int k8) {
  union { u16x4 q[2]; bf16x8 b; } u;
  const unsigned short* p = Ct + n * 268 + k8 * 8;
  u.q[0] = *(const u16x4*)p;
  u.q[1] = *(const u16x4*)(p + 4);
  return u.b;
}

// ---------------------------------------------------------------------------
// P1: cast weights fp32 -> bf16; zero the K-softmax denominator accumulator.
__global__ __launch_bounds__(256) void castw(
    const float* __restrict__ wq, const float* __restrict__ wkv,
    const float* __restrict__ wo, unsigned short* __restrict__ wqb,
    unsigned short* __restrict__ wkvb, unsigned short* __restrict__ wob,
    float* __restrict__ Z) {
  int t = blockIdx.x * 256 + threadIdx.x;
  if (t < B_ * C_) Z[t] = 0.f;
  int i = t * 4;
  const float* src;
  unsigned short* dst;
  int off;
  if (i < 65536) { src = wq; dst = wqb; off = i; }
  else if (i < 196608) { src = wkv; dst = wkvb; off = i - 65536; }
  else { src = wo; dst = wob; off = i - 196608; }
  float4 v = *(const float4*)(src + off);
  *(u16x4*)(dst + off) = (u16x4){f2bf(v.x), f2bf(v.y), f2bf(v.z), f2bf(v.w)};
}

// ---------------------------------------------------------------------------
// qproj path: qT[b][n][m] = softmax_d((wq @ x + bq) * 0.25). M-tile 128
// (2 heads) x N-tile 128, BK=64. Wave (w>>1) owns one head; (w&1) a 64-col
// half. acc[4][4].
__device__ __forceinline__ void qproj_body(
    unsigned short* As, unsigned short* Bs, const unsigned short* __restrict__ wqb,
    const float* __restrict__ x, const float* __restrict__ bq,
    unsigned short* __restrict__ qT, int b, int n0, int m0b) {
  const int tid = threadIdx.x, lane = tid & 63, w = tid >> 6;
  const int m0w = (w >> 1) * 64;
  const int n0w = (w & 1) * 64;
  const int colL = lane & 15, kq = lane >> 4, quad = lane >> 4;
  const float* xb = x + (size_t)b * C_ * N_;

  f32x4 acc[4][4];
#pragma unroll
  for (int i = 0; i < 4; i++)
#pragma unroll
    for (int j = 0; j < 4; j++) acc[i][j] = (f32x4){0.f, 0.f, 0.f, 0.f};

  float4 pbv[8];
  loadB(pbv, xb, N_, n0, 0, w, lane);

  for (int kt = 0; kt < 4; kt++) {
    writeB(Bs, pbv, w, lane);
    stage<128>(As, wqb + (size_t)m0b * C_ + kt * 64, C_, w, lane);
    __syncthreads();
    if (kt < 3) loadB(pbv, xb, N_, n0, kt + 1, w, lane);
#pragma unroll
    for (int ks = 0; ks < 2; ks++) {
      bf16x8 af[4], bf[4];
#pragma unroll
      for (int mt = 0; mt < 4; mt++) af[mt] = frag(As, m0w + mt * 16 + colL, ks * 4 + kq);
#pragma unroll
      for (int nt = 0; nt < 4; nt++) bf[nt] = fragB(Bs, n0w + nt * 16 + colL, ks * 4 + kq);
#pragma unroll
      for (int mt = 0; mt < 4; mt++)
#pragma unroll
        for (int nt = 0; nt < 4; nt++) acc[mt][nt] = mfma16(af[mt], bf[nt], acc[mt][nt]);
    }
    __syncthreads();
  }

  // per-column softmax over this wave's head (64 channels)
#pragma unroll
  for (int nt = 0; nt < 4; nt++) {
    float v[16];
    float mx = -1e30f;
#pragma unroll
    for (int mt = 0; mt < 4; mt++)
#pragma unroll
      for (int r = 0; r < 4; r++) {
        int m = m0b + m0w + mt * 16 + quad * 4 + r;
        float val = (acc[mt][nt][r] + bq[m]) * 0.25f;
        v[mt * 4 + r] = val;
        mx = fmaxf(mx, val);
      }
    mx = fmaxf(mx, __shfl_xor(mx, 16));
    mx = fmaxf(mx, __shfl_xor(mx, 32));
    float s = 0.f;
#pragma unroll
    for (int j = 0; j < 16; j++) { v[j] = __expf(v[j] - mx); s += v[j]; }
    s += __shfl_xor(s, 16);
    s += __shfl_xor(s, 32);
    float inv = 1.0f / s;
    const int n = n0 + n0w + nt * 16 + colL;
    unsigned short* qb = qT + ((size_t)b * N_ + n) * C_ + m0b + m0w;
#pragma unroll
    for (int mt = 0; mt < 4; mt++) {
      u16x4 o = (u16x4){f2bf(v[mt * 4 + 0] * inv), f2bf(v[mt * 4 + 1] * inv),
                        f2bf(v[mt * 4 + 2] * inv), f2bf(v[mt * 4 + 3] * inv)};
      *(u16x4*)(qb + mt * 16 + quad * 4) = o;
    }
  }
}

// kvproj path: KV = wkv @ cproj + bkv. M-tile 128 x N-tile 128. acc[2][8].
// Epilogue: K rows -> Eb = bf16(exp(K+b)) + rowsum Z atomics; V rows -> bf16.
__device__ __forceinline__ void kvproj_body(
    unsigned short* As, unsigned short* Bs, const unsigned short* __restrict__ wkvb,
    const float* __restrict__ cp, const float* __restrict__ bkv,
    unsigned short* __restrict__ Eb, unsigned short* __restrict__ Vb,
    float* __restrict__ Z, int b, int n0, int m0b) {
  const int tid = threadIdx.x, lane = tid & 63, w = tid >> 6;
  const int m0w = w * 32;
  const int colL = lane & 15, kq = lane >> 4, quad = lane >> 4;
  const float* cpb = cp + (size_t)b * C_ * N_;

  f32x4 acc[2][8];
#pragma unroll
  for (int i = 0; i < 2; i++)
#pragma unroll
    for (int j = 0; j < 8; j++) acc[i][j] = (f32x4){0.f, 0.f, 0.f, 0.f};

  float4 pbv[8];
  loadB(pbv, cpb, N_, n0, 0, w, lane);

  for (int kt = 0; kt < 4; kt++) {
    writeB(Bs, pbv, w, lane);
    stage<128>(As, wkvb + (size_t)m0b * C_ + kt * 64, C_, w, lane);
    __syncthreads();
    if (kt < 3) loadB(pbv, cpb, N_, n0, kt + 1, w, lane);
#pragma unroll
    for (int ks = 0; ks < 2; ks++) {
      bf16x8 bf[8];
#pragma unroll
      for (int nt = 0; nt < 8; nt++) bf[nt] = fragB(Bs, nt * 16 + colL, ks * 4 + kq);
#pragma unroll
      for (int mt = 0; mt < 2; mt++) {
        bf16x8 af = frag(As, m0w + mt * 16 + colL, ks * 4 + kq);
#pragma unroll
        for (int nt = 0; nt < 8; nt++) acc[mt][nt] = mfma16(af, bf[nt], acc[mt][nt]);
      }
    }
    __syncthreads();
  }

#pragma unroll
  for (int mt = 0; mt < 2; mt++)
#pragma unroll
    for (int r = 0; r < 4; r++) {
      int m = m0b + m0w + mt * 16 + quad * 4 + r;
      float bias = bkv[m];
      if (m < C_) {
        unsigned short* er = Eb + ((size_t)b * C_ + m) * N_ + n0;
        float es = 0.f;
#pragma unroll
        for (int nt = 0; nt < 8; nt++) {
          float e = __expf(acc[mt][nt][r] + bias);
          er[nt * 16 + colL] = f2bf(e);
          es += e;
        }
        // reduce over the 16 colL lanes of this quad (same m)
        es += __shfl_xor(es, 1);
        es += __shfl_xor(es, 2);
        es += __shfl_xor(es, 4);
        es += __shfl_xor(es, 8);
        if ((lane & 15) == 0) atomicAdd(&Z[b * C_ + m], es);
      } else {
        unsigned short* vr = Vb + ((size_t)b * C_ + m - C_) * N_ + n0;
#pragma unroll
        for (int nt = 0; nt < 8; nt++) vr[nt * 16 + colL] = f2bf(acc[mt][nt][r] + bias);
      }
    }
}

// G1+G2 fused: qproj (y=0..1) and kvproj (y=2..5), dispatch (32,6,8).
// Keep this 2D grid — panel-siblings are 32 apart in linear id, 32%8==0,
// so HW round-robin co-locates them per XCD; the mixed q/kv per-block phase
// timing also desynchronizes the drain bursts (R14's split regressed 4x).
__global__ __launch_bounds__(256) void qkvproj(
    const unsigned short* __restrict__ wqb, const unsigned short* __restrict__ wkvb,
    const float* __restrict__ x, const float* __restrict__ cp,
    const float* __restrict__ bq, const float* __restrict__ bkv,
    unsigned short* __restrict__ qT, unsigned short* __restrict__ Eb,
    unsigned short* __restrict__ Vb, float* __restrict__ Z) {
  __shared__ __align__(16) unsigned short As[128 * 64];
  __shared__ __align__(16) unsigned short Bs[128 * 68];
  const int b = blockIdx.z, n0 = blockIdx.x * 128;
  if (blockIdx.y < 2)
    qproj_body(As, Bs, wqb, x, bq, qT, b, n0, blockIdx.y * 128);
  else
    kvproj_body(As, Bs, wkvb, cp, bkv, Eb, Vb, Z, b, n0, (blockIdx.y - 2) * 128);
}

// ---------------------------------------------------------------------------
// G4: ctxp[s][b][c][d] = bf16( invz[c] * sum_{n in split s} Eb[c,n]*Vb[d,n] ).
// NT GEMM 128x128, BK=64, NSPLIT=16, XCD-chunked. T4 counted-vmcnt pipeline
// (R13 form — measured neutral, kept).
__global__ __launch_bounds__(256) void ctx_part(
    const unsigned short* __restrict__ Eb, const float* __restrict__ Z,
    const unsigned short* __restrict__ Vb, unsigned short* __restrict__ ctxp) {
  __shared__ __align__(16) unsigned short As[2][128 * 64];
  __shared__ __align__(16) unsigned short Bs[2][128 * 64];
  const int bid = blockIdx.x;
  const int swz = (bid & 7) * 64 + (bid >> 3);
  const int b = swz >> 6, r = swz & 63;
  const int s = r >> 2;
  const int m0 = ((r >> 1) & 1) * 128, n0 = (r & 1) * 128;
  const int tid = threadIdx.x, lane = tid & 63, w = tid >> 6;
  const int m0w = (w & 1) * 64, n0w = (w >> 1) * 64;
  const int colL = lane & 15, kq = lane >> 4, quad = lane >> 4;
  const unsigned short* Ag = Eb + ((size_t)b * C_ + m0) * N_ + s * (N_ / NSPLIT);
  const unsigned short* Bg = Vb + ((size_t)b * C_ + n0) * N_ + s * (N_ / NSPLIT);

  f32x4 acc[4][4];
#pragma unroll
  for (int i = 0; i < 4; i++)
#pragma unroll
    for (int j = 0; j < 4; j++) acc[i][j] = (f32x4){0.f, 0.f, 0.f, 0.f};

  stage<128>(As[0], Ag + 0 * 64, N_, w, lane);
  stage<128>(Bs[0], Bg + 0 * 64, N_, w, lane);
  stage<128>(As[1], Ag + 1 * 64, N_, w, lane);
  stage<128>(Bs[1], Bg + 1 * 64, N_, w, lane);
  VMWAIT(8);   // tile 0 landed (tile 1's 8 still in flight)
  BAR();

  for (int kt = 0; kt < 4; kt++) {
    const unsigned short* Asc = As[kt & 1];
    const unsigned short* Bsc = Bs[kt & 1];
#pragma unroll
    for (int ks = 0; ks < 2; ks++) {
      bf16x8 af[4], bf[4];
#pragma unroll
      for (int mt = 0; mt < 4; mt++) af[mt] = frag(Asc, m0w + mt * 16 + colL, ks * 4 + kq);
#pragma unroll
      for (int nt = 0; nt < 4; nt++) bf[nt] = frag(Bsc, n0w + nt * 16 + colL, ks * 4 + kq);
#pragma unroll
      for (int mt = 0; mt < 4; mt++)
#pragma unroll
        for (int nt = 0; nt < 4; nt++) acc[mt][nt] = mfma16(af[mt], bf[nt], acc[mt][nt]);
    }
    if (kt == 3) break;
    BAR();                                  // all waves done reading buf[kt&1]
    if (kt + 2 < 4) {
      stage<128>(As[kt & 1], Ag + (kt + 2) * 64, N_, w, lane);
      stage<128>(Bs[kt & 1], Bg + (kt + 2) * 64, N_, w, lane);
      VMWAIT(8);                            // tile kt+1 landed; kt+2 in flight
    } else {
      VMWAIT(0);                            // final tile (issued one iter ago)
    }
    BAR();
  }

  unsigned short* outp = ctxp + ((size_t)s * B_ + b) * C_ * C_;
  const float* Zb = Z + b * C_;
#pragma unroll
  for (int mt = 0; mt < 4; mt++)
#pragma unroll
    for (int r2 = 0; r2 < 4; r2++) {
      int m = m0 + m0w + mt * 16 + quad * 4 + r2;
      float iz = 1.0f / Zb[m];
#pragma unroll
      for (int nt = 0; nt < 4; nt++) {
        int n = n0 + n0w + nt * 16 + colL;
        outp[(size_t)m * C_ + n] = f2bf(acc[mt][nt][r2] * iz);
      }
    }
}

// ---------------------------------------------------------------------------
// R+G5 fused: ctx2[b][o][d] = wo @ (sum_s ctxp[s]). XCD-chunked: 256 blocks
// 1D, chunk 32 = one b -> ctxp[.][b] (2 MB) + wob (0.5 MB) in one L2.
__global__ __launch_bounds__(256) void ctxoproj(
    const unsigned short* __restrict__ ctxp, const unsigned short* __restrict__ wob,
    unsigned short* __restrict__ ctx2) {
  __shared__ __align__(16) unsigned short AsW[4 * 64 * 64];
  __shared__ __align__(16) unsigned short Ct[32 * 268];
  const int bid = blockIdx.x;
  const int swz = (bid & 7) * 32 + (bid >> 3);
  const int b = swz >> 5, r = swz & 31;
  const int o0 = (r >> 3) * 64, d0 = (r & 7) * 32;
  const int tid = threadIdx.x, lane = tid & 63, w = tid >> 6;
  const int colL = lane & 15, kq = lane >> 4, quad = lane >> 4;

  // wo tile 64 x 256 bf16, all 4 k-chunks async up front (hidden under phase 1)
#pragma unroll
  for (int ck = 0; ck < 4; ck++)
    stage<64>(AsW + ck * 4096, wob + (size_t)o0 * C_ + ck * 64, C_, w, lane);

  // phase 1: Ct[d][c] = sum_s ctxp[s][b][c][d0+d] (bf16 in, fp32 accumulate)
  const int q = tid & 7, cl = tid >> 3;   // q: d-quad (4 d), cl: c within pass
  const unsigned short* pb = ctxp + ((size_t)b * C_ + cl) * C_ + d0 + q * 4;
#pragma unroll 2
  for (int p = 0; p < 8; p++) {
    f32x4 s4 = (f32x4){0.f, 0.f, 0.f, 0.f};
    const unsigned short* pp = pb + (size_t)p * 32 * C_;
#pragma unroll
    for (int s = 0; s < NSPLIT; s++) {
      u16x4 v = *(const u16x4*)(pp + (size_t)s * B_ * C_ * C_);
      s4[0] += bf2f(v[0]); s4[1] += bf2f(v[1]);
      s4[2] += bf2f(v[2]); s4[3] += bf2f(v[3]);
    }
    const int c = p * 32 + cl;
#pragma unroll
    for (int j = 0; j < 4; j++) Ct[(q * 4 + j) * 268 + c] = f2bf(s4[j]);
  }
  __syncthreads();

  // phase 2: per wave 16 o-rows x 32 d-cols, K = 256
  f32x4 acc2[2];
  acc2[0] = (f32x4){0.f, 0.f, 0.f, 0.f};
  acc2[1] = (f32x4){0.f, 0.f, 0.f, 0.f};
#pragma unroll
  for (int kt = 0; kt < 4; kt++)
#pragma unroll
    for (int ks = 0; ks < 2; ks++) {
      bf16x8 af = frag(AsW + kt * 4096, w * 16 + colL, ks * 4 + kq);
#pragma unroll
      for (int nt = 0; nt < 2; nt++) {
        bf16x8 bf = fragC(Ct, nt * 16 + colL, kt * 8 + ks * 4 + kq);
        acc2[nt] = mfma16(af, bf, acc2[nt]);
      }
    }
  unsigned short* ob = ctx2 + (size_t)b * C_ * C_;
#pragma unroll
  for (int nt = 0; nt < 2; nt++)
#pragma unroll
    for (int r2 = 0; r2 < 4; r2++)
      ob[(size_t)(o0 + w * 16 + quad * 4 + r2) * C_ + d0 + nt * 16 + colL] =
          f2bf(acc2[nt][r2]);
}

// ---------------------------------------------------------------------------
// G6: out[b][m][n] = sum_d ctx2[b][m][d] * qT[b][n][d] + bo[m]. NT GEMM,
// M-tile 128 x N-tile 64, BK=64, XCD-chunked, T4 counted-vmcnt pipeline
// (6 gld_lds/wave/tile -> vmcnt(6)). R13 form.
__global__ __launch_bounds__(256) void outgemm(
    const unsigned short* __restrict__ ctx2, const unsigned short* __restrict__ qT,
    const float* __restrict__ bo, float* __restrict__ out) {
  __shared__ __align__(16) unsigned short As[2][128 * 64];
  __shared__ __align__(16) unsigned short Bs[2][64 * 64];
  const int bid = blockIdx.x;
  const int swz = (bid & 7) * 128 + (bid >> 3);
  const int b = swz >> 7, r = swz & 127;
  const int m0b = (r >> 6) * 128, n0 = (r & 63) * 64;
  const int tid = threadIdx.x, lane = tid & 63, w = tid >> 6;
  const int m0w = w * 32;
  const int colL = lane & 15, kq = lane >> 4, quad = lane >> 4;
  const unsigned short* Ag = ctx2 + (size_t)b * C_ * C_ + (size_t)m0b * C_;
  const unsigned short* Bg = qT + ((size_t)b * N_ + n0) * C_;

  f32x4 acc[2][4];
#pragma unroll
  for (int i = 0; i < 2; i++)
#pragma unroll
    for (int j = 0; j < 4; j++) acc[i][j] = (f32x4){0.f, 0.f, 0.f, 0.f};

  stage<128>(As[0], Ag + 0 * 64, C_, w, lane);
  stage<64>(Bs[0], Bg + 0 * 64, C_, w, lane);
  stage<128>(As[1], Ag + 1 * 64, C_, w, lane);
  stage<64>(Bs[1], Bg + 1 * 64, C_, w, lane);
  VMWAIT(6);   // tile 0 landed (tile 1's 6 in flight)
  BAR();

  for (int kt = 0; kt < 4; kt++) {
    const unsigned short* Asc = As[kt & 1];
    const unsigned short* Bsc = Bs[kt & 1];
#pragma unroll
    for (int ks = 0; ks < 2; ks++) {
      bf16x8 af[2], bf[4];
#pragma unroll
      for (int mt = 0; mt < 2; mt++) af[mt] = frag(Asc, m0w + mt * 16 + colL, ks * 4 + kq);
#pragma unroll
      for (int nt = 0; nt < 4; nt++) bf[nt] = frag(Bsc, nt * 16 + colL, ks * 4 + kq);
#pragma unroll
      for (int mt = 0; mt < 2; mt++)
#pragma unroll
        for (int nt = 0; nt < 4; nt++) acc[mt][nt] = mfma16(af[mt], bf[nt], acc[mt][nt]);
    }
    if (kt == 3) break;
    BAR();
    if (kt + 2 < 4) {
      stage<128>(As[kt & 1], Ag + (kt + 2) * 64, C_, w, lane);
      stage<64>(Bs[kt & 1], Bg + (kt + 2) * 64, C_, w, lane);
      VMWAIT(6);
    } else {
      VMWAIT(0);
    }
    BAR();
  }

  float* ob = out + (size_t)b * C_ * N_;
#pragma unroll
  for (int mt = 0; mt < 2; mt++)
#pragma unroll
    for (int r2 = 0; r2 < 4; r2++) {
      int m = m0b + m0w + mt * 16 + quad * 4 + r2;
      float bias = bo[m];
#pragma unroll
      for (int nt = 0; nt < 4; nt++) {
        int n = n0 + nt * 16 + colL;
        ob[(size_t)m * N_ + n] = acc[mt][nt][r2] + bias;
      }
    }
}

// ---------------------------------------------------------------------------
extern "C" void kernel_launch(void* const* d_in, const int* in_sizes, int n_in,
                              void* d_out, int out_size, void* d_ws, size_t ws_size,
                              hipStream_t stream) {
  const float* x     = (const float*)d_in[0];
  const float* cproj = (const float*)d_in[1];
  const float* wq    = (const float*)d_in[2];
  const float* bq    = (const float*)d_in[3];
  const float* wkv   = (const float*)d_in[4];
  const float* bkv   = (const float*)d_in[5];
  const float* wo    = (const float*)d_in[6];
  const float* bo    = (const float*)d_in[7];
  float* out = (float*)d_out;

  // workspace (~70 MB)
  unsigned short* qT    = (unsigned short*)d_ws;            // 8.39M u16
  unsigned short* Eb    = qT + 8388608;                     // 8.39M u16
  unsigned short* Vb    = Eb + 8388608;                     // 8.39M u16
  unsigned short* ctxp  = Vb + 8388608;                     // 8.39M u16 (16 splits, bf16)
  unsigned short* wqb   = ctxp + 8388608;
  unsigned short* wkvb  = wqb + 65536;
  unsigned short* wob   = wkvb + 131072;
  unsigned short* ctx2  = wob + 65536;                      // 524288 u16
  float*          Zbuf  = (float*)(ctx2 + 524288);          // 2048 f32

  castw<<<256, 256, 0, stream>>>(wq, wkv, wo, wqb, wkvb, wob, Zbuf);
  qkvproj<<<dim3(32, 6, 8), 256, 0, stream>>>(wqb, wkvb, x, cproj, bq, bkv,
                                              qT, Eb, Vb, Zbuf);
  ctx_part<<<512, 256, 0, stream>>>(Eb, Zbuf, Vb, ctxp);
  ctxoproj<<<256, 256, 0, stream>>>(ctxp, wob, ctx2);
  outgemm<<<1024, 256, 0, stream>>>(ctx2, qT, bo, out);
}

// Round 17
// 178.011 us; speedup vs baseline: 1.3931x; 1.0264x over previous
//
#include <hip/hip_runtime.h>

#define B_ 8
#define C_ 256
#define N_ 4096
#define NSPLIT 16

typedef float f32x4 __attribute__((ext_vector_type(4)));
typedef __bf16 bf16x8 __attribute__((ext_vector_type(8)));
typedef __bf16 bf16x4 __attribute__((ext_vector_type(4)));
typedef unsigned short u16x8 __attribute__((ext_vector_type(8)));
typedef unsigned short u16x4 __attribute__((ext_vector_type(4)));

// Native cast: compiler emits v_cvt_pk_bf16_f32 for adjacent pairs (RNE).
__device__ __forceinline__ unsigned short f2bf(float f) {
  return __builtin_bit_cast(unsigned short, (__bf16)f);
}
__device__ __forceinline__ float bf2f(unsigned short u) {
  return __uint_as_float((unsigned)u << 16);
}

__device__ __forceinline__ f32x4 mfma16(bf16x8 a, bf16x8 b, f32x4 c) {
  return __builtin_amdgcn_mfma_f32_16x16x32_bf16(a, b, c, 0, 0, 0);
}

typedef __attribute__((address_space(1))) const void* gvp;
typedef __attribute__((address_space(3))) void* lvp;
__device__ __forceinline__ void gld16(const void* g, void* l) {
  __builtin_amdgcn_global_load_lds((gvp)g, (lvp)l, 16, 0, 0);
}

// Counted waits + raw barrier (T4 pattern; neutral but harmless per R13).
#define VMWAIT(N) do { asm volatile("s_waitcnt vmcnt(" #N ")" ::: "memory"); \
                       __builtin_amdgcn_sched_barrier(0); } while (0)
#define BAR() __builtin_amdgcn_s_barrier()

// Swizzled LDS tile (bf16 sources): ROWS x 64 bf16, pitch 64 u16; chunk c of
// row r at slot c^(r&7). Staged with global_load_lds (16 B/lane, async).
// Per-wave vmem count: ROWS/32 instructions.
template <int ROWS>
__device__ __forceinline__ void stage(unsigned short* lds, const unsigned short* g,
                                      int ld, int w, int lane) {
  const int r8 = lane >> 3;
  const int ce = ((lane & 7) ^ r8) << 3;
  const unsigned short* gp = g + (size_t)(w * (ROWS / 4) + r8) * ld + ce;
  unsigned short* lp = lds + w * (ROWS / 4) * 64;
#pragma unroll
  for (int i = 0; i < ROWS / 32; i++)
    gld16(gp + (size_t)(i * 8) * ld, lp + i * 512);
}

__device__ __forceinline__ bf16x8 frag(const unsigned short* lds, int row, int kc) {
  return *(const bf16x8*)(lds + row * 64 + ((kc ^ (row & 7)) << 3));
}

// Fused-transpose B tile (fp32 [k][n] source -> bf16 [n][k] LDS, pitch 68).
// PITCH MUST BE == 0 mod 4 u16: bf16x4/u16x4 accesses need 8 B alignment
// (R15's pitch-70 broke alignment -> ds ops split to b32 -> 2.3x slower).
__device__ __forceinline__ void loadB(float4* pbv, const float* src, int ld,
                                      int n0, int kt, int w, int lane) {
  const int nf = lane & 15, kg = lane >> 4;
  const float* sp = src + (size_t)(kt * 64 + w * 16 + kg * 4) * ld + n0 + 4 * nf;
#pragma unroll
  for (int h = 0; h < 2; h++)
#pragma unroll
    for (int i = 0; i < 4; i++)
      pbv[h * 4 + i] = *(const float4*)(sp + h * 64 + (size_t)i * ld);
}
__device__ __forceinline__ void writeB(unsigned short* Bs, const float4* pbv,
                                       int w, int lane) {
  const int nf = lane & 15, kg = lane >> 4;
  const int k0 = w * 16 + kg * 4;
#pragma unroll
  for (int h = 0; h < 2; h++)
#pragma unroll
    for (int j = 0; j < 4; j++) {
      bf16x4 o = (bf16x4){(__bf16)((const float*)&pbv[h * 4 + 0])[j],
                          (__bf16)((const float*)&pbv[h * 4 + 1])[j],
                          (__bf16)((const float*)&pbv[h * 4 + 2])[j],
                          (__bf16)((const float*)&pbv[h * 4 + 3])[j]};
      *(bf16x4*)&Bs[(h * 64 + 4 * nf + j) * 68 + k0] = o;
    }
}
__device__ __forceinline__ bf16x8 fragB(const unsigned short* Bs, int n, int k8) {
  union { u16x4 q[2]; bf16x8 b; } u;
  const unsigned short* p = Bs + n * 68 + k8 * 8;
  u.q[0] = *(const u16x4*)p;
  u.q[1] = *(const u16x4*)(p + 4);
  return u.b;
}

// ctx^T tile in LDS, pitch 268 u16 (0 mod 4; row stride 6 banks mod 32 ->
// conflict-free).
__device__ __forceinline__ bf16x8 fragC(const unsigned short* Ct, int n, int k8) {
  union { u16x4 q[2]; bf16x8 b; } u;
  const unsigned short* p = Ct + n * 268 + k8 * 8;
  u.q[0] = *(const u16x4*)p;
  u.q[1] = *(const u16x4*)(p + 4);
  return u.b;
}

// ---------------------------------------------------------------------------
// P1: cast weights fp32 -> bf16; zero the K-softmax denominator accumulator.
__global__ __launch_bounds__(256) void castw(
    const float* __restrict__ wq, const float* __restrict__ wkv,
    const float* __restrict__ wo, unsigned short* __restrict__ wqb,
    unsigned short* __restrict__ wkvb, unsigned short* __restrict__ wob,
    float* __restrict__ Z) {
  int t = blockIdx.x * 256 + threadIdx.x;
  if (t < B_ * C_) Z[t] = 0.f;
  int i = t * 4;
  const float* src;
  unsigned short* dst;
  int off;
  if (i < 65536) { src = wq; dst = wqb; off = i; }
  else if (i < 196608) { src = wkv; dst = wkvb; off = i - 65536; }
  else { src = wo; dst = wob; off = i - 196608; }
  float4 v = *(const float4*)(src + off);
  *(u16x4*)(dst + off) = (u16x4){f2bf(v.x), f2bf(v.y), f2bf(v.z), f2bf(v.w)};
}

// ---------------------------------------------------------------------------
// qproj path: qT[b][n][m] = softmax_d((wq @ x + bq) * 0.25). M-tile 128
// (2 heads) x N-tile 128, BK=64. Wave (w>>1) owns one head; (w&1) a 64-col
// half. acc[4][4].
__device__ __forceinline__ void qproj_body(
    unsigned short* As, unsigned short* Bs, const unsigned short* __restrict__ wqb,
    const float* __restrict__ x, const float* __restrict__ bq,
    unsigned short* __restrict__ qT, int b, int n0, int m0b) {
  const int tid = threadIdx.x, lane = tid & 63, w = tid >> 6;
  const int m0w = (w >> 1) * 64;
  const int n0w = (w & 1) * 64;
  const int colL = lane & 15, kq = lane >> 4, quad = lane >> 4;
  const float* xb = x + (size_t)b * C_ * N_;

  f32x4 acc[4][4];
#pragma unroll
  for (int i = 0; i < 4; i++)
#pragma unroll
    for (int j = 0; j < 4; j++) acc[i][j] = (f32x4){0.f, 0.f, 0.f, 0.f};

  float4 pbv[8];
  loadB(pbv, xb, N_, n0, 0, w, lane);

  for (int kt = 0; kt < 4; kt++) {
    writeB(Bs, pbv, w, lane);
    stage<128>(As, wqb + (size_t)m0b * C_ + kt * 64, C_, w, lane);
    __syncthreads();
    if (kt < 3) loadB(pbv, xb, N_, n0, kt + 1, w, lane);
#pragma unroll
    for (int ks = 0; ks < 2; ks++) {
      bf16x8 af[4], bf[4];
#pragma unroll
      for (int mt = 0; mt < 4; mt++) af[mt] = frag(As, m0w + mt * 16 + colL, ks * 4 + kq);
#pragma unroll
      for (int nt = 0; nt < 4; nt++) bf[nt] = fragB(Bs, n0w + nt * 16 + colL, ks * 4 + kq);
#pragma unroll
      for (int mt = 0; mt < 4; mt++)
#pragma unroll
        for (int nt = 0; nt < 4; nt++) acc[mt][nt] = mfma16(af[mt], bf[nt], acc[mt][nt]);
    }
    __syncthreads();
  }

  // per-column softmax over this wave's head (64 channels)
#pragma unroll
  for (int nt = 0; nt < 4; nt++) {
    float v[16];
    float mx = -1e30f;
#pragma unroll
    for (int mt = 0; mt < 4; mt++)
#pragma unroll
      for (int r = 0; r < 4; r++) {
        int m = m0b + m0w + mt * 16 + quad * 4 + r;
        float val = (acc[mt][nt][r] + bq[m]) * 0.25f;
        v[mt * 4 + r] = val;
        mx = fmaxf(mx, val);
      }
    mx = fmaxf(mx, __shfl_xor(mx, 16));
    mx = fmaxf(mx, __shfl_xor(mx, 32));
    float s = 0.f;
#pragma unroll
    for (int j = 0; j < 16; j++) { v[j] = __expf(v[j] - mx); s += v[j]; }
    s += __shfl_xor(s, 16);
    s += __shfl_xor(s, 32);
    float inv = 1.0f / s;
    const int n = n0 + n0w + nt * 16 + colL;
    unsigned short* qb = qT + ((size_t)b * N_ + n) * C_ + m0b + m0w;
#pragma unroll
    for (int mt = 0; mt < 4; mt++) {
      u16x4 o = (u16x4){f2bf(v[mt * 4 + 0] * inv), f2bf(v[mt * 4 + 1] * inv),
                        f2bf(v[mt * 4 + 2] * inv), f2bf(v[mt * 4 + 3] * inv)};
      *(u16x4*)(qb + mt * 16 + quad * 4) = o;
    }
  }
}

// kvproj path: KV = wkv @ cproj + bkv. M-tile 128 x N-tile 128. acc[2][8].
// Epilogue: K rows -> Eb = bf16(exp(K+b)) + rowsum Z atomics; V rows -> bf16.
__device__ __forceinline__ void kvproj_body(
    unsigned short* As, unsigned short* Bs, const unsigned short* __restrict__ wkvb,
    const float* __restrict__ cp, const float* __restrict__ bkv,
    unsigned short* __restrict__ Eb, unsigned short* __restrict__ Vb,
    float* __restrict__ Z, int b, int n0, int m0b) {
  const int tid = threadIdx.x, lane = tid & 63, w = tid >> 6;
  const int m0w = w * 32;
  const int colL = lane & 15, kq = lane >> 4, quad = lane >> 4;
  const float* cpb = cp + (size_t)b * C_ * N_;

  f32x4 acc[2][8];
#pragma unroll
  for (int i = 0; i < 2; i++)
#pragma unroll
    for (int j = 0; j < 8; j++) acc[i][j] = (f32x4){0.f, 0.f, 0.f, 0.f};

  float4 pbv[8];
  loadB(pbv, cpb, N_, n0, 0, w, lane);

  for (int kt = 0; kt < 4; kt++) {
    writeB(Bs, pbv, w, lane);
    stage<128>(As, wkvb + (size_t)m0b * C_ + kt * 64, C_, w, lane);
    __syncthreads();
    if (kt < 3) loadB(pbv, cpb, N_, n0, kt + 1, w, lane);
#pragma unroll
    for (int ks = 0; ks < 2; ks++) {
      bf16x8 bf[8];
#pragma unroll
      for (int nt = 0; nt < 8; nt++) bf[nt] = fragB(Bs, nt * 16 + colL, ks * 4 + kq);
#pragma unroll
      for (int mt = 0; mt < 2; mt++) {
        bf16x8 af = frag(As, m0w + mt * 16 + colL, ks * 4 + kq);
#pragma unroll
        for (int nt = 0; nt < 8; nt++) acc[mt][nt] = mfma16(af, bf[nt], acc[mt][nt]);
      }
    }
    __syncthreads();
  }

#pragma unroll
  for (int mt = 0; mt < 2; mt++)
#pragma unroll
    for (int r = 0; r < 4; r++) {
      int m = m0b + m0w + mt * 16 + quad * 4 + r;
      float bias = bkv[m];
      if (m < C_) {
        unsigned short* er = Eb + ((size_t)b * C_ + m) * N_ + n0;
        float es = 0.f;
#pragma unroll
        for (int nt = 0; nt < 8; nt++) {
          float e = __expf(acc[mt][nt][r] + bias);
          er[nt * 16 + colL] = f2bf(e);
          es += e;
        }
        // reduce over the 16 colL lanes of this quad (same m)
        es += __shfl_xor(es, 1);
        es += __shfl_xor(es, 2);
        es += __shfl_xor(es, 4);
        es += __shfl_xor(es, 8);
        if ((lane & 15) == 0) atomicAdd(&Z[b * C_ + m], es);
      } else {
        unsigned short* vr = Vb + ((size_t)b * C_ + m - C_) * N_ + n0;
#pragma unroll
        for (int nt = 0; nt < 8; nt++) vr[nt * 16 + colL] = f2bf(acc[mt][nt][r] + bias);
      }
    }
}

// G1+G2 fused: qproj (y=0..1) and kvproj (y=2..5), dispatch (32,6,8).
// Keep this 2D grid — panel-siblings are 32 apart in linear id, 32%8==0,
// so HW round-robin co-locates them per XCD; the mixed q/kv per-block phase
// timing also desynchronizes the drain bursts (R14's split regressed 4x).
__global__ __launch_bounds__(256) void qkvproj(
    const unsigned short* __restrict__ wqb, const unsigned short* __restrict__ wkvb,
    const float* __restrict__ x, const float* __restrict__ cp,
    const float* __restrict__ bq, const float* __restrict__ bkv,
    unsigned short* __restrict__ qT, unsigned short* __restrict__ Eb,
    unsigned short* __restrict__ Vb, float* __restrict__ Z) {
  __shared__ __align__(16) unsigned short As[128 * 64];
  __shared__ __align__(16) unsigned short Bs[128 * 68];
  const int b = blockIdx.z, n0 = blockIdx.x * 128;
  if (blockIdx.y < 2)
    qproj_body(As, Bs, wqb, x, bq, qT, b, n0, blockIdx.y * 128);
  else
    kvproj_body(As, Bs, wkvb, cp, bkv, Eb, Vb, Z, b, n0, (blockIdx.y - 2) * 128);
}

// ---------------------------------------------------------------------------
// G4: ctxp[s][b][c][d] = bf16( invz[c] * sum_{n in split s} Eb[c,n]*Vb[d,n] ).
// NT GEMM 128x128, BK=64, NSPLIT=16, XCD-chunked. T4 counted-vmcnt pipeline
// (R13 form — measured neutral, kept).
__global__ __launch_bounds__(256) void ctx_part(
    const unsigned short* __restrict__ Eb, const float* __restrict__ Z,
    const unsigned short* __restrict__ Vb, unsigned short* __restrict__ ctxp) {
  __shared__ __align__(16) unsigned short As[2][128 * 64];
  __shared__ __align__(16) unsigned short Bs[2][128 * 64];
  const int bid = blockIdx.x;
  const int swz = (bid & 7) * 64 + (bid >> 3);
  const int b = swz >> 6, r = swz & 63;
  const int s = r >> 2;
  const int m0 = ((r >> 1) & 1) * 128, n0 = (r & 1) * 128;
  const int tid = threadIdx.x, lane = tid & 63, w = tid >> 6;
  const int m0w = (w & 1) * 64, n0w = (w >> 1) * 64;
  const int colL = lane & 15, kq = lane >> 4, quad = lane >> 4;
  const unsigned short* Ag = Eb + ((size_t)b * C_ + m0) * N_ + s * (N_ / NSPLIT);
  const unsigned short* Bg = Vb + ((size_t)b * C_ + n0) * N_ + s * (N_ / NSPLIT);

  f32x4 acc[4][4];
#pragma unroll
  for (int i = 0; i < 4; i++)
#pragma unroll
    for (int j = 0; j < 4; j++) acc[i][j] = (f32x4){0.f, 0.f, 0.f, 0.f};

  stage<128>(As[0], Ag + 0 * 64, N_, w, lane);
  stage<128>(Bs[0], Bg + 0 * 64, N_, w, lane);
  stage<128>(As[1], Ag + 1 * 64, N_, w, lane);
  stage<128>(Bs[1], Bg + 1 * 64, N_, w, lane);
  VMWAIT(8);   // tile 0 landed (tile 1's 8 still in flight)
  BAR();

  for (int kt = 0; kt < 4; kt++) {
    const unsigned short* Asc = As[kt & 1];
    const unsigned short* Bsc = Bs[kt & 1];
#pragma unroll
    for (int ks = 0; ks < 2; ks++) {
      bf16x8 af[4], bf[4];
#pragma unroll
      for (int mt = 0; mt < 4; mt++) af[mt] = frag(Asc, m0w + mt * 16 + colL, ks * 4 + kq);
#pragma unroll
      for (int nt = 0; nt < 4; nt++) bf[nt] = frag(Bsc, n0w + nt * 16 + colL, ks * 4 + kq);
#pragma unroll
      for (int mt = 0; mt < 4; mt++)
#pragma unroll
        for (int nt = 0; nt < 4; nt++) acc[mt][nt] = mfma16(af[mt], bf[nt], acc[mt][nt]);
    }
    if (kt == 3) break;
    BAR();                                  // all waves done reading buf[kt&1]
    if (kt + 2 < 4) {
      stage<128>(As[kt & 1], Ag + (kt + 2) * 64, N_, w, lane);
      stage<128>(Bs[kt & 1], Bg + (kt + 2) * 64, N_, w, lane);
      VMWAIT(8);                            // tile kt+1 landed; kt+2 in flight
    } else {
      VMWAIT(0);                            // final tile (issued one iter ago)
    }
    BAR();
  }

  unsigned short* outp = ctxp + ((size_t)s * B_ + b) * C_ * C_;
  const float* Zb = Z + b * C_;
#pragma unroll
  for (int mt = 0; mt < 4; mt++)
#pragma unroll
    for (int r2 = 0; r2 < 4; r2++) {
      int m = m0 + m0w + mt * 16 + quad * 4 + r2;
      float iz = 1.0f / Zb[m];
#pragma unroll
      for (int nt = 0; nt < 4; nt++) {
        int n = n0 + n0w + nt * 16 + colL;
        outp[(size_t)m * C_ + n] = f2bf(acc[mt][nt][r2] * iz);
      }
    }
}

// ---------------------------------------------------------------------------
// R+G5 fused: ctx2[b][o][d] = wo @ (sum_s ctxp[s]). XCD-chunked: 256 blocks
// 1D, chunk 32 = one b -> ctxp[.][b] (2 MB) + wob (0.5 MB) in one L2.
__global__ __launch_bounds__(256) void ctxoproj(
    const unsigned short* __restrict__ ctxp, const unsigned short* __restrict__ wob,
    unsigned short* __restrict__ ctx2) {
  __shared__ __align__(16) unsigned short AsW[4 * 64 * 64];
  __shared__ __align__(16) unsigned short Ct[32 * 268];
  const int bid = blockIdx.x;
  const int swz = (bid & 7) * 32 + (bid >> 3);
  const int b = swz >> 5, r = swz & 31;
  const int o0 = (r >> 3) * 64, d0 = (r & 7) * 32;
  const int tid = threadIdx.x, lane = tid & 63, w = tid >> 6;
  const int colL = lane & 15, kq = lane >> 4, quad = lane >> 4;

  // wo tile 64 x 256 bf16, all 4 k-chunks async up front (hidden under phase 1)
#pragma unroll
  for (int ck = 0; ck < 4; ck++)
    stage<64>(AsW + ck * 4096, wob + (size_t)o0 * C_ + ck * 64, C_, w, lane);

  // phase 1: Ct[d][c] = sum_s ctxp[s][b][c][d0+d] (bf16 in, fp32 accumulate)
  const int q = tid & 7, cl = tid >> 3;   // q: d-quad (4 d), cl: c within pass
  const unsigned short* pb = ctxp + ((size_t)b * C_ + cl) * C_ + d0 + q * 4;
#pragma unroll 2
  for (int p = 0; p < 8; p++) {
    f32x4 s4 = (f32x4){0.f, 0.f, 0.f, 0.f};
    const unsigned short* pp = pb + (size_t)p * 32 * C_;
#pragma unroll
    for (int s = 0; s < NSPLIT; s++) {
      u16x4 v = *(const u16x4*)(pp + (size_t)s * B_ * C_ * C_);
      s4[0] += bf2f(v[0]); s4[1] += bf2f(v[1]);
      s4[2] += bf2f(v[2]); s4[3] += bf2f(v[3]);
    }
    const int c = p * 32 + cl;
#pragma unroll
    for (int j = 0; j < 4; j++) Ct[(q * 4 + j) * 268 + c] = f2bf(s4[j]);
  }
  __syncthreads();

  // phase 2: per wave 16 o-rows x 32 d-cols, K = 256
  f32x4 acc2[2];
  acc2[0] = (f32x4){0.f, 0.f, 0.f, 0.f};
  acc2[1] = (f32x4){0.f, 0.f, 0.f, 0.f};
#pragma unroll
  for (int kt = 0; kt < 4; kt++)
#pragma unroll
    for (int ks = 0; ks < 2; ks++) {
      bf16x8 af = frag(AsW + kt * 4096, w * 16 + colL, ks * 4 + kq);
#pragma unroll
      for (int nt = 0; nt < 2; nt++) {
        bf16x8 bf = fragC(Ct, nt * 16 + colL, kt * 8 + ks * 4 + kq);
        acc2[nt] = mfma16(af, bf, acc2[nt]);
      }
    }
  unsigned short* ob = ctx2 + (size_t)b * C_ * C_;
#pragma unroll
  for (int nt = 0; nt < 2; nt++)
#pragma unroll
    for (int r2 = 0; r2 < 4; r2++)
      ob[(size_t)(o0 + w * 16 + quad * 4 + r2) * C_ + d0 + nt * 16 + colL] =
          f2bf(acc2[nt][r2]);
}

// ---------------------------------------------------------------------------
// G6: out[b][m][n] = sum_d ctx2[b][m][d] * qT[b][n][d] + bo[m]. NT GEMM,
// M-tile 256 (full C: qT read ONCE, -16.8 MB vs M=128) x N-tile 64, BK=64.
// 512 blocks, XCD-chunked (chunk 64 = one b). Single-buffer form, 40 KB LDS
// -> 4 blocks/CU, 2 dispatch rounds (desynchronized regime).
__global__ __launch_bounds__(256) void outgemm(
    const unsigned short* __restrict__ ctx2, const unsigned short* __restrict__ qT,
    const float* __restrict__ bo, float* __restrict__ out) {
  __shared__ __align__(16) unsigned short As[256 * 64];
  __shared__ __align__(16) unsigned short Bs[64 * 64];
  const int bid = blockIdx.x;
  const int swz = (bid & 7) * 64 + (bid >> 3);
  const int b = swz >> 6, n0 = (swz & 63) * 64;
  const int tid = threadIdx.x, lane = tid & 63, w = tid >> 6;
  const int m0w = w * 64;
  const int colL = lane & 15, kq = lane >> 4, quad = lane >> 4;
  const unsigned short* Ag = ctx2 + (size_t)b * C_ * C_;
  const unsigned short* Bg = qT + ((size_t)b * N_ + n0) * C_;

  f32x4 acc[4][4];
#pragma unroll
  for (int i = 0; i < 4; i++)
#pragma unroll
    for (int j = 0; j < 4; j++) acc[i][j] = (f32x4){0.f, 0.f, 0.f, 0.f};

  for (int kt = 0; kt < 4; kt++) {
    stage<256>(As, Ag + kt * 64, C_, w, lane);
    stage<64>(Bs, Bg + kt * 64, C_, w, lane);
    __syncthreads();
#pragma unroll
    for (int ks = 0; ks < 2; ks++) {
      bf16x8 af[4], bf[4];
#pragma unroll
      for (int mt = 0; mt < 4; mt++) af[mt] = frag(As, m0w + mt * 16 + colL, ks * 4 + kq);
#pragma unroll
      for (int nt = 0; nt < 4; nt++) bf[nt] = frag(Bs, nt * 16 + colL, ks * 4 + kq);
#pragma unroll
      for (int mt = 0; mt < 4; mt++)
#pragma unroll
        for (int nt = 0; nt < 4; nt++) acc[mt][nt] = mfma16(af[mt], bf[nt], acc[mt][nt]);
    }
    __syncthreads();
  }

  float* ob = out + (size_t)b * C_ * N_;
#pragma unroll
  for (int mt = 0; mt < 4; mt++)
#pragma unroll
    for (int r2 = 0; r2 < 4; r2++) {
      int m = m0w + mt * 16 + quad * 4 + r2;
      float bias = bo[m];
#pragma unroll
      for (int nt = 0; nt < 4; nt++) {
        int n = n0 + nt * 16 + colL;
        ob[(size_t)m * N_ + n] = acc[mt][nt][r2] + bias;
      }
    }
}

// ---------------------------------------------------------------------------
extern "C" void kernel_launch(void* const* d_in, const int* in_sizes, int n_in,
                              void* d_out, int out_size, void* d_ws, size_t ws_size,
                              hipStream_t stream) {
  const float* x     = (const float*)d_in[0];
  const float* cproj = (const float*)d_in[1];
  const float* wq    = (const float*)d_in[2];
  const float* bq    = (const float*)d_in[3];
  const float* wkv   = (const float*)d_in[4];
  const float* bkv   = (const float*)d_in[5];
  const float* wo    = (const float*)d_in[6];
  const float* bo    = (const float*)d_in[7];
  float* out = (float*)d_out;

  // workspace (~70 MB)
  unsigned short* qT    = (unsigned short*)d_ws;            // 8.39M u16
  unsigned short* Eb    = qT + 8388608;                     // 8.39M u16
  unsigned short* Vb    = Eb + 8388608;                     // 8.39M u16
  unsigned short* ctxp  = Vb + 8388608;                     // 8.39M u16 (16 splits, bf16)
  unsigned short* wqb   = ctxp + 8388608;
  unsigned short* wkvb  = wqb + 65536;
  unsigned short* wob   = wkvb + 131072;
  unsigned short* ctx2  = wob + 65536;                      // 524288 u16
  float*          Zbuf  = (float*)(ctx2 + 524288);          // 2048 f32

  castw<<<256, 256, 0, stream>>>(wq, wkv, wo, wqb, wkvb, wob, Zbuf);
  qkvproj<<<dim3(32, 6, 8), 256, 0, stream>>>(wqb, wkvb, x, cproj, bq, bkv,
                                              qT, Eb, Vb, Zbuf);
  ctx_part<<<512, 256, 0, stream>>>(Eb, Zbuf, Vb, ctxp);
  ctxoproj<<<256, 256, 0, stream>>>(ctxp, wob, ctx2);
  outgemm<<<512, 256, 0, stream>>>(ctx2, qT, bo, out);
}